// Round 16
// baseline (234.871 us; speedup 1.0000x reference)
//
#include <hip/hip_runtime.h>
#include <cstdint>
#include <cstddef>

#define BB 2
#define NN 6
#define CINC 256
#define HH 16
#define WW 44
#define DD 59
#define CO 64
#define PIXN 704       // H*W
#define OTOT 123       // D+COUT
#define XX 128
#define YY 128
#define ZZ 7

// ---------------- kernel 0: lapack_lite-style replica of inv(f32) via
// sgetrf (sgetf2: iamax strict->, full-row swap, recip-multiply scal, unfused
// ger) + SGETRI: strti2 on U (diag = 1/a by DIVISION, strmv axpy, sscal by
// -ajj), unblocked right-to-left column sweep (work copy, zero, gemv axpy),
// then COLUMN interchanges. All mul/add separately rounded (contraction
// proven irrelevant in R13 vs R15).
__global__ void k_inv(const float* __restrict__ c2e, float* __restrict__ e2c) {
  int t = threadIdx.x;
  if (t >= BB * NN) return;
  const float* M = c2e + t * 16;
  float A[4][4];
  int ipiv[4];
  for (int i = 0; i < 4; ++i)
    for (int j = 0; j < 4; ++j) A[i][j] = M[i * 4 + j];
  // ---- sgetf2 ----
  for (int j = 0; j < 4; ++j) {
    int p = j;
    float mx = fabsf(A[j][j]);
    for (int i = j + 1; i < 4; ++i) {
      float v = fabsf(A[i][j]);
      if (v > mx) { mx = v; p = i; }
    }
    ipiv[j] = p;
    if (p != j)
      for (int k = 0; k < 4; ++k) { float tmp = A[j][k]; A[j][k] = A[p][k]; A[p][k] = tmp; }
    if (j < 3) {
      float r = __fdiv_rn(1.0f, A[j][j]);          // ONE/A(J,J), then sscal multiply
      for (int i = j + 1; i < 4; ++i) A[i][j] = __fmul_rn(A[i][j], r);
      for (int i = j + 1; i < 4; ++i)             // sger, unfused
        for (int k = j + 1; k < 4; ++k)
          A[i][k] = __fsub_rn(A[i][k], __fmul_rn(A[i][j], A[j][k]));
    }
  }
  // ---- strti2: invert U in place ----
  for (int j = 0; j < 4; ++j) {
    A[j][j] = __fdiv_rn(1.0f, A[j][j]);           // DIVISION (netlib strti2)
    float ajj = -A[j][j];
    // strmv('U','N','N', j) on x = A[0..j-1][j]
    for (int j2 = 0; j2 < j; ++j2) {
      float temp = A[j2][j];
      if (temp != 0.0f) {
        for (int i = 0; i < j2; ++i)
          A[i][j] = __fadd_rn(A[i][j], __fmul_rn(temp, A[i][j2]));
        A[j2][j] = __fmul_rn(temp, A[j2][j2]);
      }
    }
    // sscal(j, ajj, x)
    for (int i = 0; i < j; ++i)
      A[i][j] = __fmul_rn(ajj, A[i][j]);
  }
  // ---- sgetri unblocked sweep: solve inv(A)*L = inv(U) ----
  float work[4];
  for (int j = 3; j >= 0; --j) {
    for (int i = j + 1; i < 4; ++i) { work[i] = A[i][j]; A[i][j] = 0.0f; }
    for (int k = j + 1; k < 4; ++k) {
      float temp = -work[k];
      for (int i = 0; i < 4; ++i)
        A[i][j] = __fadd_rn(A[i][j], __fmul_rn(temp, A[i][k]));
    }
  }
  // ---- column interchanges (J = N-1 .. 1) ----
  for (int j = 2; j >= 0; --j) {
    int jp = ipiv[j];
    if (jp != j)
      for (int i = 0; i < 4; ++i) { float tmp = A[i][j]; A[i][j] = A[i][jp]; A[i][jp] = tmp; }
  }
  float* O = e2c + t * 12;
  for (int i = 0; i < 3; ++i)
    for (int j = 0; j < 4; ++j) O[i * 4 + j] = A[i][j];
}

// ---------------- kernel 1: 1x1-conv GEMM + softmax + feat writeback
// grid: 12 bn * 11 pixel-tiles of 64 = 132 blocks, 512 threads (8 waves).
// lane = pixel within tile, wave owns 16 output channels -> W loads wave-uniform.
__global__ __launch_bounds__(512) void k_gemm(const float* __restrict__ img,
    const float* __restrict__ wd, const float* __restrict__ bd,
    float* __restrict__ depth_out, float* __restrict__ feat_ws) {
  __shared__ float buf[8448];       // union: staged F-tile (8192) / xsT transpose (64*129)
  __shared__ float pm[8 * 64];
  __shared__ float psum[8 * 64];
  __shared__ float m_l[64], rs_l[64];
  const int tid  = threadIdx.x;
  const int lane = tid & 63;
  const int wv   = __builtin_amdgcn_readfirstlane(tid >> 6);
  const int bn   = blockIdx.x / 11;
  const int tile = blockIdx.x % 11;
  const int px0  = tile * 64;
  const float* src = img + (size_t)bn * CINC * PIXN + px0;

  float acc[16];
#pragma unroll
  for (int j = 0; j < 16; ++j) {
    int o = wv * 16 + j;
    acc[j] = (o < OTOT) ? bd[o] : 0.f;
  }

  for (int chunk = 0; chunk < 2; ++chunk) {
    __syncthreads();
    // stage 128 c x 64 px, interleaved [cq][px][cr] for ds_read_b128
#pragma unroll
    for (int it = 0; it < 4; ++it) {
      int idx = it * 512 + tid;
      int c = idx >> 4, q = idx & 15;
      float4 v = *(const float4*)(src + (size_t)(chunk * 128 + c) * PIXN + q * 4);
      int cq = c >> 2, cr = c & 3;
      int base = (cq * 64 + q * 4) * 4 + cr;
      buf[base + 0 * 4] = v.x;
      buf[base + 1 * 4] = v.y;
      buf[base + 2 * 4] = v.z;
      buf[base + 3 * 4] = v.w;
    }
    __syncthreads();
    const float* wrow = wd + chunk * 128;
    for (int cq = 0; cq < 32; ++cq) {
      float4 f = *(const float4*)&buf[(cq * 64 + lane) * 4];
#pragma unroll
      for (int j = 0; j < 16; ++j) {
        int o = wv * 16 + j;
        if (o < OTOT) {
          float4 w4 = *(const float4*)(wrow + o * 256 + cq * 4);
          acc[j] += f.x * w4.x;
          acc[j] += f.y * w4.y;
          acc[j] += f.z * w4.z;
          acc[j] += f.w * w4.w;
        }
      }
    }
  }
  __syncthreads();
  // transpose: buf[px*129 + o]
#pragma unroll
  for (int j = 0; j < 16; ++j) {
    int o = wv * 16 + j;
    if (o < OTOT) buf[lane * 129 + o] = acc[j];
  }
  __syncthreads();
  // softmax stats over d in [0,59), 8 d-slices in parallel
  const int px  = tid & 63;
  const int rep = tid >> 6;
  const int d0 = rep * 8;
  const int d1 = (d0 + 8 < DD) ? d0 + 8 : DD;
  float mm = -3.4e38f;
  for (int d = d0; d < d1; ++d) mm = fmaxf(mm, buf[px * 129 + d]);
  pm[rep * 64 + px] = mm;
  __syncthreads();
  float m = pm[px];
#pragma unroll
  for (int r2 = 1; r2 < 8; ++r2) m = fmaxf(m, pm[r2 * 64 + px]);
  float ss = 0.f;
  for (int d = d0; d < d1; ++d) ss += expf(buf[px * 129 + d] - m);
  psum[rep * 64 + px] = ss;
  __syncthreads();
  float s = psum[px];
#pragma unroll
  for (int r2 = 1; r2 < 8; ++r2) s += psum[r2 * 64 + px];
  if (rep == 0) { m_l[px] = m; rs_l[px] = 1.f / s; }
  __syncthreads();
  // depth out: (bn, pix, d) contiguous in d -> fully coalesced chunk of 64*59
  float* drow = depth_out + ((size_t)bn * PIXN + px0) * DD;
  for (int idx = tid; idx < 64 * DD; idx += 512) {
    int p2 = idx / DD;
    int d  = idx - p2 * DD;
    drow[idx] = expf(buf[p2 * 129 + d] - m_l[p2]) * rs_l[p2];
  }
  // feat ws: (bn, pix, o) contiguous in o
  float* frow = feat_ws + ((size_t)bn * PIXN + px0) * CO;
  for (int idx = tid; idx < 64 * CO; idx += 512) {
    int p2 = idx >> 6, of = idx & 63;
    frow[idx] = buf[p2 * 129 + 59 + of];
  }
}

// ---------------- kernel 2: per-(b,x,y,n,z) projection -> weight + pixel index
// Scalar-sequential einsum (no-SIMD numpy build): products individually
// rounded, accumulated left-to-right: dot4 = rn(rn(rn(p0+p1)+p2)+p3), no FMA.
// K einsum count=3 -> scalar sequential, order-immune due to K's zeros.
__global__ __launch_bounds__(256) void k_proj(const float* __restrict__ e2c,
    const float* __restrict__ Kin, const float* __restrict__ depth_out,
    float* __restrict__ w_ws, unsigned short* __restrict__ pix_ws) {
  int t = blockIdx.x * 256 + threadIdx.x;
  const int TOT = BB * YY * XX * 48;
  if (t >= TOT) return;
  int cell = t / 48;
  int nz = t - cell * 48;
  int b = cell >> 14;
  int rem = cell & 16383;
  int y = rem >> 7;
  int x = rem & 127;
  int n = nz >> 3;
  int z = nz & 7;
  float w = 0.f;
  int pix = 0;
  if (z < ZZ) {
    int bn = b * NN + n;
    const float* M = e2c + bn * 12;
    float vx = __fadd_rn(__fmul_rn((float)x, 0.8f), -51.2f);
    float vy = __fadd_rn(__fmul_rn((float)y, 0.8f), -51.2f);
    float vz = __fadd_rn(__fmul_rn((float)z, 1.0f), -2.5f);
    // sequential: ((p0 + p1) + p2) + p3, p3 = m3*1 = m3
    float c0 = __fadd_rn(__fadd_rn(__fadd_rn(__fmul_rn(M[0], vx), __fmul_rn(M[1], vy)),
                                   __fmul_rn(M[2], vz)), M[3]);
    float c1 = __fadd_rn(__fadd_rn(__fadd_rn(__fmul_rn(M[4], vx), __fmul_rn(M[5], vy)),
                                   __fmul_rn(M[6], vz)), M[7]);
    float zc = __fadd_rn(__fadd_rn(__fadd_rn(__fmul_rn(M[8], vx), __fmul_rn(M[9], vy)),
                                   __fmul_rn(M[10], vz)), M[11]);
    bool val = (zc > 0.5f);
    float zs = fmaxf(zc, 0.1f);
    float u = __fdiv_rn(c0, zs);
    float v = __fdiv_rn(c1, zs);
    const float* Kp = Kin + bn * 9;
    // K einsum row0: (fx*u + 0*v) + cx ; row1: (0*u + fy*v) + cy — order-immune
    float imx = __fadd_rn(__fmul_rn(Kp[0], u), Kp[2]);
    float imy = __fadd_rn(__fmul_rn(Kp[4], v), Kp[5]);
    float fcx = __fmul_rn(imx, 0.0625f);   // /16 exact
    float fcy = __fmul_rn(imy, 0.0625f);
    val = val && (fcx >= 0.f) && (fcx < 44.f) && (fcy >= 0.f) && (fcy < 16.f);
    int dbin = (int)truncf(__fsub_rn(zc, 1.0f));
    val = val && (dbin >= 0) && (dbin < DD);
    int ui = (int)truncf(fminf(fmaxf(fcx, 0.f), 43.f));
    int vi = (int)truncf(fminf(fmaxf(fcy, 0.f), 15.f));
    int d = min(max(dbin, 0), DD - 1);
    pix = vi * WW + ui;
    if (val) w = depth_out[((size_t)bn * PIXN + pix) * DD + d];
  }
  w_ws[t] = w;
  pix_ws[t] = (unsigned short)pix;
}

// ---------------- kernel 3: gather-accumulate into BEV
// block = 1024 thr = 16 waves = 16 consecutive x cells of one (b,y) row; lane = channel.
__global__ __launch_bounds__(1024) void k_scatter(const float* __restrict__ w_ws,
    const unsigned short* __restrict__ pix_ws, const float* __restrict__ feat_ws,
    float* __restrict__ bev) {
  __shared__ float sm[64 * 17];
  int gb = blockIdx.x;
  int b = gb >> 10;
  int rem = gb & 1023;
  int y = rem >> 3;
  int x0 = (rem & 7) << 4;
  int tid = threadIdx.x;
  int lane = tid & 63;
  int wv = tid >> 6;
  int x = x0 + wv;
  int base = ((b * YY + y) * XX + x) * 48;
  float wval = 0.f;
  int pixv = 0;
  if (lane < 48) {
    wval = w_ws[base + lane];
    pixv = pix_ws[base + lane];
  }
  unsigned long long mask = __ballot(wval != 0.f);
  float acc = 0.f;
  while (mask) {
    int s = __builtin_ctzll(mask);
    mask &= (mask - 1);
    float wb = __shfl(wval, s);
    int pb = __shfl(pixv, s);
    int n = s >> 3;
    const float* fr = feat_ws + (((size_t)(b * NN + n) * PIXN + pb) << 6);
    acc = fmaf(wb, fr[lane], acc);
  }
  sm[lane * 17 + wv] = acc;
  __syncthreads();
  int o = tid >> 4, xi = tid & 15;
  bev[(((size_t)b * CO + o) * YY + y) * XX + x0 + xi] = sm[o * 17 + xi];
}

extern "C" void kernel_launch(void* const* d_in, const int* in_sizes, int n_in,
                              void* d_out, int out_size, void* d_ws, size_t ws_size,
                              hipStream_t stream) {
  const float* img = (const float*)d_in[0];
  const float* c2e = (const float*)d_in[1];
  const float* Kin = (const float*)d_in[2];
  const float* wd  = (const float*)d_in[3];
  const float* bd  = (const float*)d_in[4];

  float* bev = (float*)d_out;
  float* depth_out = bev + (size_t)BB * CO * YY * XX;   // 2,097,152 floats in

  // workspace layout
  float* e2c = (float*)d_ws;                            // 144 floats (pad to 2048 B)
  float* feat_ws = (float*)((char*)d_ws + 2048);        // 540,672 floats
  float* w_ws = feat_ws + (size_t)BB * NN * PIXN * CO;  // 1,572,864 floats
  unsigned short* pix_ws = (unsigned short*)(w_ws + (size_t)BB * YY * XX * 48);

  hipLaunchKernelGGL(k_inv, dim3(1), dim3(64), 0, stream, c2e, e2c);
  hipLaunchKernelGGL(k_gemm, dim3(132), dim3(512), 0, stream, img, wd, bd, depth_out, feat_ws);
  hipLaunchKernelGGL(k_proj, dim3((BB * YY * XX * 48) / 256), dim3(256), 0, stream,
                     e2c, Kin, depth_out, w_ws, pix_ws);
  hipLaunchKernelGGL(k_scatter, dim3(BB * YY * 8), dim3(1024), 0, stream,
                     w_ws, pix_ws, feat_ws, bev);
}

// Round 17
// 192.166 us; speedup vs baseline: 1.2222x; 1.2222x over previous
//
#include <hip/hip_runtime.h>
#include <cstdint>
#include <cstddef>

#define BB 2
#define NN 6
#define CINC 256
#define HH 16
#define WW 44
#define DD 59
#define CO 64
#define PIXN 704       // H*W
#define OTOT 123       // D+COUT
#define XX 128
#define YY 128
#define ZZ 7

// ---------------- kernel 0: lapack_lite-style replica of inv(f32) via
// sgetrf (sgetf2: iamax strict->, full-row swap, recip-multiply scal, unfused
// ger) + SGETRI: strti2 on U (diag = 1/a by DIVISION, strmv axpy, sscal by
// -ajj), unblocked right-to-left column sweep, then COLUMN interchanges.
// All mul/add separately rounded. DO NOT TOUCH — numerics verified (R16 PASS).
__global__ void k_inv(const float* __restrict__ c2e, float* __restrict__ e2c) {
  int t = threadIdx.x;
  if (t >= BB * NN) return;
  const float* M = c2e + t * 16;
  float A[4][4];
  int ipiv[4];
  for (int i = 0; i < 4; ++i)
    for (int j = 0; j < 4; ++j) A[i][j] = M[i * 4 + j];
  // ---- sgetf2 ----
  for (int j = 0; j < 4; ++j) {
    int p = j;
    float mx = fabsf(A[j][j]);
    for (int i = j + 1; i < 4; ++i) {
      float v = fabsf(A[i][j]);
      if (v > mx) { mx = v; p = i; }
    }
    ipiv[j] = p;
    if (p != j)
      for (int k = 0; k < 4; ++k) { float tmp = A[j][k]; A[j][k] = A[p][k]; A[p][k] = tmp; }
    if (j < 3) {
      float r = __fdiv_rn(1.0f, A[j][j]);
      for (int i = j + 1; i < 4; ++i) A[i][j] = __fmul_rn(A[i][j], r);
      for (int i = j + 1; i < 4; ++i)
        for (int k = j + 1; k < 4; ++k)
          A[i][k] = __fsub_rn(A[i][k], __fmul_rn(A[i][j], A[j][k]));
    }
  }
  // ---- strti2 ----
  for (int j = 0; j < 4; ++j) {
    A[j][j] = __fdiv_rn(1.0f, A[j][j]);
    float ajj = -A[j][j];
    for (int j2 = 0; j2 < j; ++j2) {
      float temp = A[j2][j];
      if (temp != 0.0f) {
        for (int i = 0; i < j2; ++i)
          A[i][j] = __fadd_rn(A[i][j], __fmul_rn(temp, A[i][j2]));
        A[j2][j] = __fmul_rn(temp, A[j2][j2]);
      }
    }
    for (int i = 0; i < j; ++i)
      A[i][j] = __fmul_rn(ajj, A[i][j]);
  }
  // ---- sgetri sweep ----
  float work[4];
  for (int j = 3; j >= 0; --j) {
    for (int i = j + 1; i < 4; ++i) { work[i] = A[i][j]; A[i][j] = 0.0f; }
    for (int k = j + 1; k < 4; ++k) {
      float temp = -work[k];
      for (int i = 0; i < 4; ++i)
        A[i][j] = __fadd_rn(A[i][j], __fmul_rn(temp, A[i][k]));
    }
  }
  // ---- column interchanges ----
  for (int j = 2; j >= 0; --j) {
    int jp = ipiv[j];
    if (jp != j)
      for (int i = 0; i < 4; ++i) { float tmp = A[i][j]; A[i][j] = A[i][jp]; A[i][jp] = tmp; }
  }
  float* O = e2c + t * 12;
  for (int i = 0; i < 3; ++i)
    for (int j = 0; j < 4; ++j) O[i * 4 + j] = A[i][j];
}

// ---------------- kernel 1: 1x1-conv GEMM + softmax + feat writeback
// v2: W chunk staged in LDS (was: 16 serialized wave-uniform global loads per
// cq iteration -> ~4800 cyc/cq scalar-wait; now ds broadcast, ~free).
__global__ __launch_bounds__(512) void k_gemm(const float* __restrict__ img,
    const float* __restrict__ wd, const float* __restrict__ bd,
    float* __restrict__ depth_out, float* __restrict__ feat_ws) {
  __shared__ float fbuf[8448];        // F chunk [cq][px][cr] (8192) / transpose (64*129)
  __shared__ float wbuf[OTOT * 128];  // W chunk [o][k] 63.0 KB
  __shared__ float pm[8 * 64];
  __shared__ float psum[8 * 64];
  __shared__ float m_l[64], rs_l[64];
  const int tid  = threadIdx.x;
  const int lane = tid & 63;
  const int wv   = __builtin_amdgcn_readfirstlane(tid >> 6);
  const int bn   = blockIdx.x / 11;
  const int tile = blockIdx.x % 11;
  const int px0  = tile * 64;
  const float* src = img + (size_t)bn * CINC * PIXN + px0;

  float acc[16];
#pragma unroll
  for (int j = 0; j < 16; ++j) {
    int o = wv * 16 + j;
    acc[j] = (o < OTOT) ? bd[o] : 0.f;
  }

  for (int chunk = 0; chunk < 2; ++chunk) {
    __syncthreads();
    // stage W chunk: 123 outs x 128 k, coalesced float4
    for (int idx = tid; idx < OTOT * 32; idx += 512) {
      int o = idx >> 5, kq = idx & 31;
      float4 w4 = *(const float4*)(wd + o * 256 + chunk * 128 + kq * 4);
      *(float4*)(wbuf + o * 128 + kq * 4) = w4;
    }
    // stage F chunk: 128 c x 64 px, interleaved [cq][px][cr] for ds_read_b128
#pragma unroll
    for (int it = 0; it < 4; ++it) {
      int idx = it * 512 + tid;
      int c = idx >> 4, q = idx & 15;
      float4 v = *(const float4*)(src + (size_t)(chunk * 128 + c) * PIXN + q * 4);
      int cq = c >> 2, cr = c & 3;
      int base = (cq * 64 + q * 4) * 4 + cr;
      fbuf[base + 0 * 4] = v.x;
      fbuf[base + 1 * 4] = v.y;
      fbuf[base + 2 * 4] = v.z;
      fbuf[base + 3 * 4] = v.w;
    }
    __syncthreads();
    for (int cq = 0; cq < 32; ++cq) {
      float4 f = *(const float4*)&fbuf[(cq * 64 + lane) * 4];
#pragma unroll
      for (int j = 0; j < 16; ++j) {
        int o = wv * 16 + j;
        if (o < OTOT) {
          float4 w4 = *(const float4*)(wbuf + o * 128 + cq * 4);  // broadcast
          acc[j] += f.x * w4.x;
          acc[j] += f.y * w4.y;
          acc[j] += f.z * w4.z;
          acc[j] += f.w * w4.w;
        }
      }
    }
  }
  __syncthreads();
  // transpose: fbuf[px*129 + o]
#pragma unroll
  for (int j = 0; j < 16; ++j) {
    int o = wv * 16 + j;
    if (o < OTOT) fbuf[lane * 129 + o] = acc[j];
  }
  __syncthreads();
  // softmax stats over d in [0,59), 8 d-slices in parallel
  const int px  = tid & 63;
  const int rep = tid >> 6;
  const int d0 = rep * 8;
  const int d1 = (d0 + 8 < DD) ? d0 + 8 : DD;
  float mm = -3.4e38f;
  for (int d = d0; d < d1; ++d) mm = fmaxf(mm, fbuf[px * 129 + d]);
  pm[rep * 64 + px] = mm;
  __syncthreads();
  float m = pm[px];
#pragma unroll
  for (int r2 = 1; r2 < 8; ++r2) m = fmaxf(m, pm[r2 * 64 + px]);
  float ss = 0.f;
  for (int d = d0; d < d1; ++d) ss += expf(fbuf[px * 129 + d] - m);
  psum[rep * 64 + px] = ss;
  __syncthreads();
  float s = psum[px];
#pragma unroll
  for (int r2 = 1; r2 < 8; ++r2) s += psum[r2 * 64 + px];
  if (rep == 0) { m_l[px] = m; rs_l[px] = 1.f / s; }
  __syncthreads();
  // depth out: (bn, pix, d) contiguous in d
  float* drow = depth_out + ((size_t)bn * PIXN + px0) * DD;
  for (int idx = tid; idx < 64 * DD; idx += 512) {
    int p2 = idx / DD;
    int d  = idx - p2 * DD;
    drow[idx] = expf(fbuf[p2 * 129 + d] - m_l[p2]) * rs_l[p2];
  }
  // feat ws: (bn, pix, o) contiguous in o
  float* frow = feat_ws + ((size_t)bn * PIXN + px0) * CO;
  for (int idx = tid; idx < 64 * CO; idx += 512) {
    int p2 = idx >> 6, of = idx & 63;
    frow[idx] = fbuf[p2 * 129 + 59 + of];
  }
}

// ---------------- kernel 2: per-(b,x,y,n,z) projection -> weight + pixel index
// Scalar-sequential einsum: dot4 = rn(rn(rn(p0+p1)+p2)+p3), no FMA.
// DO NOT TOUCH — numerics verified (R16 PASS).
__global__ __launch_bounds__(256) void k_proj(const float* __restrict__ e2c,
    const float* __restrict__ Kin, const float* __restrict__ depth_out,
    float* __restrict__ w_ws, unsigned short* __restrict__ pix_ws) {
  int t = blockIdx.x * 256 + threadIdx.x;
  const int TOT = BB * YY * XX * 48;
  if (t >= TOT) return;
  int cell = t / 48;
  int nz = t - cell * 48;
  int b = cell >> 14;
  int rem = cell & 16383;
  int y = rem >> 7;
  int x = rem & 127;
  int n = nz >> 3;
  int z = nz & 7;
  float w = 0.f;
  int pix = 0;
  if (z < ZZ) {
    int bn = b * NN + n;
    const float* M = e2c + bn * 12;
    float vx = __fadd_rn(__fmul_rn((float)x, 0.8f), -51.2f);
    float vy = __fadd_rn(__fmul_rn((float)y, 0.8f), -51.2f);
    float vz = __fadd_rn(__fmul_rn((float)z, 1.0f), -2.5f);
    float c0 = __fadd_rn(__fadd_rn(__fadd_rn(__fmul_rn(M[0], vx), __fmul_rn(M[1], vy)),
                                   __fmul_rn(M[2], vz)), M[3]);
    float c1 = __fadd_rn(__fadd_rn(__fadd_rn(__fmul_rn(M[4], vx), __fmul_rn(M[5], vy)),
                                   __fmul_rn(M[6], vz)), M[7]);
    float zc = __fadd_rn(__fadd_rn(__fadd_rn(__fmul_rn(M[8], vx), __fmul_rn(M[9], vy)),
                                   __fmul_rn(M[10], vz)), M[11]);
    bool val = (zc > 0.5f);
    float zs = fmaxf(zc, 0.1f);
    float u = __fdiv_rn(c0, zs);
    float v = __fdiv_rn(c1, zs);
    const float* Kp = Kin + bn * 9;
    float imx = __fadd_rn(__fmul_rn(Kp[0], u), Kp[2]);
    float imy = __fadd_rn(__fmul_rn(Kp[4], v), Kp[5]);
    float fcx = __fmul_rn(imx, 0.0625f);
    float fcy = __fmul_rn(imy, 0.0625f);
    val = val && (fcx >= 0.f) && (fcx < 44.f) && (fcy >= 0.f) && (fcy < 16.f);
    int dbin = (int)truncf(__fsub_rn(zc, 1.0f));
    val = val && (dbin >= 0) && (dbin < DD);
    int ui = (int)truncf(fminf(fmaxf(fcx, 0.f), 43.f));
    int vi = (int)truncf(fminf(fmaxf(fcy, 0.f), 15.f));
    int d = min(max(dbin, 0), DD - 1);
    pix = vi * WW + ui;
    if (val) w = depth_out[((size_t)bn * PIXN + pix) * DD + d];
  }
  w_ws[t] = w;
  pix_ws[t] = (unsigned short)pix;
}

// ---------------- kernel 3: gather-accumulate into BEV
__global__ __launch_bounds__(1024) void k_scatter(const float* __restrict__ w_ws,
    const unsigned short* __restrict__ pix_ws, const float* __restrict__ feat_ws,
    float* __restrict__ bev) {
  __shared__ float sm[64 * 17];
  int gb = blockIdx.x;
  int b = gb >> 10;
  int rem = gb & 1023;
  int y = rem >> 3;
  int x0 = (rem & 7) << 4;
  int tid = threadIdx.x;
  int lane = tid & 63;
  int wv = tid >> 6;
  int x = x0 + wv;
  int base = ((b * YY + y) * XX + x) * 48;
  float wval = 0.f;
  int pixv = 0;
  if (lane < 48) {
    wval = w_ws[base + lane];
    pixv = pix_ws[base + lane];
  }
  unsigned long long mask = __ballot(wval != 0.f);
  float acc = 0.f;
  while (mask) {
    int s = __builtin_ctzll(mask);
    mask &= (mask - 1);
    float wb = __shfl(wval, s);
    int pb = __shfl(pixv, s);
    int n = s >> 3;
    const float* fr = feat_ws + (((size_t)(b * NN + n) * PIXN + pb) << 6);
    acc = fmaf(wb, fr[lane], acc);
  }
  sm[lane * 17 + wv] = acc;
  __syncthreads();
  int o = tid >> 4, xi = tid & 15;
  bev[(((size_t)b * CO + o) * YY + y) * XX + x0 + xi] = sm[o * 17 + xi];
}

extern "C" void kernel_launch(void* const* d_in, const int* in_sizes, int n_in,
                              void* d_out, int out_size, void* d_ws, size_t ws_size,
                              hipStream_t stream) {
  const float* img = (const float*)d_in[0];
  const float* c2e = (const float*)d_in[1];
  const float* Kin = (const float*)d_in[2];
  const float* wd  = (const float*)d_in[3];
  const float* bd  = (const float*)d_in[4];

  float* bev = (float*)d_out;
  float* depth_out = bev + (size_t)BB * CO * YY * XX;

  float* e2c = (float*)d_ws;
  float* feat_ws = (float*)((char*)d_ws + 2048);
  float* w_ws = feat_ws + (size_t)BB * NN * PIXN * CO;
  unsigned short* pix_ws = (unsigned short*)(w_ws + (size_t)BB * YY * XX * 48);

  hipLaunchKernelGGL(k_inv, dim3(1), dim3(64), 0, stream, c2e, e2c);
  hipLaunchKernelGGL(k_gemm, dim3(132), dim3(512), 0, stream, img, wd, bd, depth_out, feat_ws);
  hipLaunchKernelGGL(k_proj, dim3((BB * YY * XX * 48) / 256), dim3(256), 0, stream,
                     e2c, Kin, depth_out, w_ws, pix_ws);
  hipLaunchKernelGGL(k_scatter, dim3(BB * YY * 8), dim3(1024), 0, stream,
                     w_ws, pix_ws, feat_ws, bev);
}